// Round 14
// baseline (155.197 us; speedup 1.0000x reference)
//
#include <hip/hip_runtime.h>
#include <math.h>

typedef unsigned long long u64;
typedef unsigned int u32;

#define B_ 2
#define F_ 8
#define P_ 2048
#define T_ 7                   // F-1
#define ROWS (B_*T_*P_)        // 28672
#define SENT_OU 0xFFFFFFFFu

// ---- keys as doubles: hi word = RAW float bits of nd (>=0 here), lo word = idx.
// For nd >= 0 the double bit pattern is positive, so IEEE double ordering ==
// integer ordering of (nd_bits, idx) == (distance, idx) lexicographic -> exact
// reference order with lower-index tie-break. CE = v_min_f64 + v_max_f64.
// (r8 measured: u64 integer CE is 1.4x MORE VALU cycles; f64 CE is the winner)
#define CED(arr,a,b) do { double _x=arr[a], _y=arr[b]; arr[a]=fmin(_x,_y); arr[b]=fmax(_x,_y); } while(0)

// Batcher odd-even mergesort, 8 elements, 19 comparators
__device__ __forceinline__ void sort8d(double* k) {
  CED(k,0,1); CED(k,2,3); CED(k,4,5); CED(k,6,7);
  CED(k,0,2); CED(k,1,3); CED(k,4,6); CED(k,5,7);
  CED(k,1,2); CED(k,5,6);
  CED(k,0,4); CED(k,1,5); CED(k,2,6); CED(k,3,7);
  CED(k,2,4); CED(k,3,5);
  CED(k,1,2); CED(k,3,4); CED(k,5,6);
}

// A,B sorted ascending -> A = lowest 8 of the 16, sorted
__device__ __forceinline__ void low8(double* A, const double* Bv) {
#pragma unroll
  for (int i = 0; i < 8; ++i) A[i] = fmin(A[i], Bv[7-i]);   // bitonic
#pragma unroll
  for (int st = 4; st >= 1; st >>= 1) {
#pragma unroll
    for (int i = 0; i < 8; ++i) {
      if ((i & st) == 0) { CED(A, i, i + st); }
    }
  }
}

// ---- quarter(16-lane)-local butterfly reductions via DPP: result in ALL lanes ----
__device__ __forceinline__ u32 bfly16_min_u32(u32 x) {
  u32 t;
  t = (u32)__builtin_amdgcn_update_dpp((int)x,(int)x,0x0B1,0xF,0xF,false); x = t<x?t:x;
  t = (u32)__builtin_amdgcn_update_dpp((int)x,(int)x,0x04E,0xF,0xF,false); x = t<x?t:x;
  t = (u32)__builtin_amdgcn_update_dpp((int)x,(int)x,0x141,0xF,0xF,false); x = t<x?t:x;
  t = (u32)__builtin_amdgcn_update_dpp((int)x,(int)x,0x140,0xF,0xF,false); x = t<x?t:x;
  return x;
}
__device__ __forceinline__ float bfly16_sum_f32(float x) {
  float t;
  t = __uint_as_float((u32)__builtin_amdgcn_update_dpp((int)__float_as_uint(x),(int)__float_as_uint(x),0x0B1,0xF,0xF,false)); x += t;
  t = __uint_as_float((u32)__builtin_amdgcn_update_dpp((int)__float_as_uint(x),(int)__float_as_uint(x),0x04E,0xF,0xF,false)); x += t;
  t = __uint_as_float((u32)__builtin_amdgcn_update_dpp((int)__float_as_uint(x),(int)__float_as_uint(x),0x141,0xF,0xF,false)); x += t;
  t = __uint_as_float((u32)__builtin_amdgcn_update_dpp((int)__float_as_uint(x),(int)__float_as_uint(x),0x140,0xF,0xF,false)); x += t;
  return x;
}

// ---------------- Kernel A1: per-frame bbox centroid ----------------
__global__ __launch_bounds__(256) void kA1_bbox(const float4* __restrict__ pts,
                                                float* __restrict__ cent) {
  int bf = blockIdx.x;                // b*F + f
  const float4* base = pts + (size_t)bf * P_;
  int tid = threadIdx.x;
  float mnx =  INFINITY, mny =  INFINITY, mnz =  INFINITY;
  float mxx = -INFINITY, mxy = -INFINITY, mxz = -INFINITY;
#pragma unroll
  for (int i = 0; i < 8; ++i) {
    float4 v = base[tid + i*256];
    mnx=fminf(mnx,v.x); mny=fminf(mny,v.y); mnz=fminf(mnz,v.z);
    mxx=fmaxf(mxx,v.x); mxy=fmaxf(mxy,v.y); mxz=fmaxf(mxz,v.z);
  }
#pragma unroll
  for (int off = 32; off >= 1; off >>= 1) {
    mnx=fminf(mnx,__shfl_xor(mnx,off)); mny=fminf(mny,__shfl_xor(mny,off)); mnz=fminf(mnz,__shfl_xor(mnz,off));
    mxx=fmaxf(mxx,__shfl_xor(mxx,off)); mxy=fmaxf(mxy,__shfl_xor(mxy,off)); mxz=fmaxf(mxz,__shfl_xor(mxz,off));
  }
  __shared__ float red[4][6];
  int wid = tid >> 6, lane = tid & 63;
  if (lane == 0) { red[wid][0]=mnx; red[wid][1]=mny; red[wid][2]=mnz;
                   red[wid][3]=mxx; red[wid][4]=mxy; red[wid][5]=mxz; }
  __syncthreads();
  if (tid == 0) {
    mnx=fminf(fminf(red[0][0],red[1][0]),fminf(red[2][0],red[3][0]));
    mny=fminf(fminf(red[0][1],red[1][1]),fminf(red[2][1],red[3][1]));
    mnz=fminf(fminf(red[0][2],red[1][2]),fminf(red[2][2],red[3][2]));
    mxx=fmaxf(fmaxf(red[0][3],red[1][3]),fmaxf(red[2][3],red[3][3]));
    mxy=fmaxf(fmaxf(red[0][4],red[1][4]),fmaxf(red[2][4],red[3][4]));
    mxz=fmaxf(fmaxf(red[0][5],red[1][5]),fmaxf(red[2][5],red[3][5]));
    cent[bf*3 + 0] = (mnx+mxx)*0.5f;
    cent[bf*3 + 1] = (mny+mxy)*0.5f;
    cent[bf*3 + 2] = (mnz+mxz)*0.5f;
  }
}

// bearing quaternion for one point (identical arithmetic across rounds)
__device__ __forceinline__ float4 bearing(float4 v, float cx, float cy, float cz) {
  float dx=v.x-cx, dy=v.y-cy, dz=v.z-cz;
  float n = sqrtf(((dx*dx) + dy*dy) + dz*dz);
  n = fmaxf(n, 1e-12f);
  float dxn = dx/n, dyn = dy/n, dzn = dz/n;
  float dotc = fminf(fmaxf(dyn, -0.99999990f), 0.99999990f);
  float half = acosf(dotc) * 0.5f;
  float an = sqrtf(dzn*dzn + dxn*dxn);
  an = fmaxf(an, 1e-12f);
  float axx = dzn/an, axz = (-dxn)/an;
  float s = sinf(half), w = cosf(half);
  return make_float4(w, axx*s, 0.f, axz*s);
}

// ---------------- Kernel AB: fused bearings + forward quats + pts2 prepack ----
__global__ __launch_bounds__(256) void kAB_qfwd(const float4* __restrict__ pts,
                                                const float* __restrict__ cent,
                                                float4* __restrict__ qf,
                                                float4* __restrict__ pts2) {
  int i = blockIdx.x*256 + threadIdx.x;   // over B*T*P
  int p = i & (P_-1);
  int t = (i >> 11) % T_;
  int b = i / (T_*P_);
  int bf0 = b*F_ + t;
  float4 v0 = pts[(size_t)bf0*P_ + p];
  float4 v1 = pts[(size_t)(bf0+1)*P_ + p];
  float4 s = bearing(v0, cent[bf0*3+0], cent[bf0*3+1], cent[bf0*3+2]);       // src (frame t)
  float4 a = bearing(v1, cent[(bf0+1)*3+0], cent[(bf0+1)*3+1], cent[(bf0+1)*3+2]); // tgt (t+1)
  float aw=a.x, ax=a.y, ay=a.z, az=a.w;
  float bw=s.x, bx=-s.y, by=-s.z, bz=-s.w;          // conj
  float w  = ((aw*bw - ax*bx) - ay*by) - az*bz;
  float xo = ((aw*bx + ax*bw) + ay*bz) - az*by;
  float yo = ((aw*by - ax*bz) + ay*bw) + az*bx;
  float zo = ((aw*bz + ax*by) - ay*bx) + az*bw;
  float n = sqrtf(((w*w + xo*xo) + yo*yo) + zo*zo);
  n = fmaxf(n, 1e-12f);
  qf[i] = make_float4(w/n, xo/n, yo/n, zo/n);
  float qs = fmaf(v0.x,v0.x, fmaf(v0.y,v0.y, v0.z*v0.z));
  pts2[(size_t)bf0*P_ + p] = make_float4(v0.x, v0.y, v0.z, qs);
}

// ---------------- Kernel C: top-40, quarter-wave rows, 4 waves/block ----------------
__device__ __forceinline__ double mkkey(float4 c, u32 q,
                                        float px, float py, float pz, float ps) {
  float dot = fmaf(px, c.x, fmaf(py, c.y, pz*c.z));
  float nd  = fmaf(-2.f, dot, ps + c.w);   // ascending distance (>= 0 here)
  return __hiloint2double(__float_as_int(nd), (int)q);
}
__device__ __forceinline__ u64 mkkey_u(float4 c, u32 q,
                                       float px, float py, float pz, float ps) {
  float dot = fmaf(px, c.x, fmaf(py, c.y, pz*c.z));
  float nd  = fmaf(-2.f, dot, ps + c.w);
  u32 u = __float_as_uint(nd);
  u32 ou = u ^ (((u32)((int)u >> 31)) | 0x80000000u);
  return ((u64)ou << 16) | q;
}

__device__ __forceinline__ void popstep(u32 (&OU)[8], u32 (&IX)[8],
                                        u32& LOU, u32& LIX, u32& CAP, int imod,
                                        int slot, const float4* __restrict__ pbase,
                                        float px, float py, float pz, float ps) {
  if (__any(OU[0] == SENT_OU)) {       // exact refill, cold (P ~ 0.4%/wave over 40 pops)
    bool need = (OU[0] == SENT_OU);
    u64 lastK = ((u64)LOU << 16) | LIX;
    u64 best = ~0ull;
    for (int j = 0; j < 128; ++j) {
      u32 q = (u32)(j*16 + slot);
      u64 kk = mkkey_u(pbase[q], q, px,py,pz,ps);
      if (kk > lastK && kk < best) best = kk;
    }
    if (need && best != ~0ull) {
      OU[0] = (u32)(best >> 16); IX[0] = (u32)(best & 0xffffu);
      LOU = OU[0]; LIX = IX[0];        // next-refill anchor for this lane
    }
  }
  u32 qmin = bfly16_min_u32(OU[0]);                  // all lanes get quarter min ou
  bool meq = (OU[0] == qmin);
  u32 tt   = meq ? IX[0] : 0xFFFFFFFFu;
  u32 widx = bfly16_min_u32(tt);                     // exact idx tie-break + broadcast
  bool iam = meq && (IX[0] == widx);
  CAP = (slot == imod) ? widx : CAP;
#pragma unroll
  for (int jj = 0; jj < 7; ++jj) {
    OU[jj] = iam ? OU[jj+1] : OU[jj];
    IX[jj] = iam ? IX[jj+1] : IX[jj];
  }
  OU[7] = iam ? SENT_OU : OU[7];
}

__global__ __launch_bounds__(256) void kC_select(const float4* __restrict__ pts2,
                                                 const float4* __restrict__ qf,
                                                 float* __restrict__ S) {
  int lane = threadIdx.x & 63;
  int wid  = threadIdx.x >> 6;         // wave within block (0..3)
  int slot = lane & 15;                // position within 16-lane quarter
  int quarter = lane >> 4;             // 0..3
  int gid = blockIdx.x * 16 + wid * 4; // first row of this wave
  int p0 = gid & (P_-1);               // 16 divides 2048 -> same tile across waves
  int bt = gid >> 11;                  // b*7 + t
  int t  = bt % T_;
  int b  = bt / T_;
  const float4* pbase = pts2 + (size_t)(b*F_ + t) * P_;

  int prow = p0 + quarter;             // this quarter's row
  float4 pw = pbase[prow];
  float px=pw.x, py=pw.y, pz=pw.z, ps=pw.w;

  // ---- sort phase: per lane 128 candidates (j*16+slot), keep sorted top-8 ----
  double acc[8];
  {
    double k0[8];
#pragma unroll
    for (int u = 0; u < 8; ++u) { float4 c = pbase[u*16 + slot];
      k0[u] = mkkey(c, (u32)(u*16 + slot), px,py,pz,ps); }
    sort8d(k0);
#pragma unroll
    for (int j = 0; j < 8; ++j) acc[j] = k0[j];
  }
#pragma unroll 2
  for (int batch = 1; batch < 16; ++batch) {
    int qb = batch*128 + slot;
    float4 c[8];
#pragma unroll
    for (int u = 0; u < 8; ++u) c[u] = pbase[qb + u*16];
    double k[8];
#pragma unroll
    for (int u = 0; u < 8; ++u) k[u] = mkkey(c[u], (u32)(qb + u*16), px,py,pz,ps);
    sort8d(k);
    low8(acc, k);
  }

  // unpack into register queue; transform raw nd bits -> ordered u32 (8 entries
  // only, vs per-candidate in the hot loop); refill anchor = acc[7]
  u32 OU[8], IX[8];
#pragma unroll
  for (int j = 0; j < 8; ++j) {
    u64 bb = (u64)__double_as_longlong(acc[j]);
    u32 hi = (u32)(bb >> 32);
    OU[j] = hi ^ (((u32)((int)hi >> 31)) | 0x80000000u);
    IX[j] = (u32)(bb & 0xffffu);
  }
  u32 lou = OU[7], lix = IX[7];
  u32 cap1=0, cap2=0, cap3=0;

#pragma unroll 1
  for (int i = 0; i < 16; ++i)         // winners 0..15 -> cap1[slot==i]
    popstep(OU, IX, lou, lix, cap1, i, slot, pbase, px,py,pz,ps);
#pragma unroll 1
  for (int i = 0; i < 16; ++i)         // winners 16..31 -> cap2
    popstep(OU, IX, lou, lix, cap2, i, slot, pbase, px,py,pz,ps);
#pragma unroll 1
  for (int i = 0; i < 8; ++i)          // winners 32..39 -> cap3 (slots 0..7)
    popstep(OU, IX, lou, lix, cap3, i, slot, pbase, px,py,pz,ps);

  // ---- epilogue: geodesic sums ----
  int row = bt*P_ + prow;
  const float4* qbt = qf + (size_t)bt * P_;
  float4 qp = qf[row];

  float4 n; float d;
  n = qbt[cap1]; d = ((qp.x*n.x + qp.y*n.y) + qp.z*n.z) + qp.w*n.w;
  float g1 = 2.f * acosf(fminf(fabsf(d), 0.99999990f));
  n = qbt[cap2]; d = ((qp.x*n.x + qp.y*n.y) + qp.z*n.z) + qp.w*n.w;
  float g2 = 2.f * acosf(fminf(fabsf(d), 0.99999990f));
  n = qbt[cap3]; d = ((qp.x*n.x + qp.y*n.y) + qp.z*n.z) + qp.w*n.w;
  float g3 = (slot < 8) ? 2.f * acosf(fminf(fabsf(d), 0.99999990f)) : 0.f;

  float s40 = bfly16_sum_f32(g1 + g2 + g3);
  float s15 = bfly16_sum_f32((slot < 15) ? g1 : 0.f);
  float s5  = bfly16_sum_f32((slot < 5)  ? g1 : 0.f);

  if (slot == 0) {
    S[0*ROWS + row] = s5  / 5.f;
    S[1*ROWS + row] = s15 / 15.f;
    S[2*ROWS + row] = s40 / 40.f;
  }
}

// ---------------- Kernel E1: per-(scale,b,p) mean over t ----------------
__global__ __launch_bounds__(256) void kE1_means(const float* __restrict__ S,
                                                 float* __restrict__ M) {
  int gid = blockIdx.x*256 + threadIdx.x;   // 0..12287 = k*4096 + j
  int k = gid >> 12;
  int j = gid & 4095;
  int b = j >> 11, p = j & 2047;
  const float* Sk = S + (size_t)k * ROWS;
  float acc = 0.f;
#pragma unroll
  for (int t = 0; t < 7; ++t) acc += Sk[(b*7 + t)*2048 + p];
  M[gid] = acc / 7.f;
}

// ---------------- Kernel E2: exact lower-median via radix-select + output ----
// lower median of 4096 = 2047th smallest (0-indexed). 4 rounds of 256-bucket
// LDS histogram on the ordered-u32 transform; integer atomics -> deterministic.
__global__ __launch_bounds__(1024) void kE2_select(const float* __restrict__ M,
                                                   float* __restrict__ out) {
  int k = blockIdx.x;                  // scale 0..2
  int tid = threadIdx.x;
  __shared__ u32 hist[256];
  __shared__ u32 sPref;
  __shared__ int sRank;
  __shared__ u32 sMax;
  __shared__ u32 wmax[16];

  float m[4]; u32 ou[4];
#pragma unroll
  for (int u = 0; u < 4; ++u) {
    int j = tid + u*1024;
    float v = M[k*4096 + j];
    m[u] = v;
    u32 bbits = __float_as_uint(v);
    ou[u] = (bbits & 0x80000000u) ? ~bbits : (bbits | 0x80000000u);
  }
  // block max (ordered u32 == float order)
  u32 mx = ou[0] > ou[1] ? ou[0] : ou[1];
  u32 mx2 = ou[2] > ou[3] ? ou[2] : ou[3];
  mx = mx > mx2 ? mx : mx2;
#pragma unroll
  for (int off = 32; off >= 1; off >>= 1) {
    u32 t = (u32)__shfl_xor((int)mx, off); mx = t > mx ? t : mx;
  }
  if ((tid & 63) == 0) wmax[tid >> 6] = mx;
  if (tid == 0) { sPref = 0u; sRank = 2047; }
  __syncthreads();
  if (tid == 0) {
    u32 g = wmax[0];
#pragma unroll
    for (int w = 1; w < 16; ++w) g = wmax[w] > g ? wmax[w] : g;
    sMax = g;
  }
  // 4 radix rounds (8 bits each, MSB first)
  for (int r = 0; r < 4; ++r) {
    if (tid < 256) hist[tid] = 0u;
    __syncthreads();
    u32 pmask = (r == 0) ? 0u : (0xFFFFFFFFu << (32 - 8*r));
    u32 pref = sPref;
    int sh = 24 - 8*r;
#pragma unroll
    for (int u = 0; u < 4; ++u) {
      if ((ou[u] & pmask) == pref)
        atomicAdd(&hist[(ou[u] >> sh) & 255u], 1u);
    }
    __syncthreads();
    if (tid == 0) {
      int rk = sRank; u32 cum = 0;
      for (int bb = 0; bb < 256; ++bb) {
        u32 c = hist[bb];
        if (cum + c > (u32)rk) { sPref = pref | ((u32)bb << sh); sRank = rk - (int)cum; break; }
        cum += c;
      }
    }
    __syncthreads();
  }
  // invert ordered transform
  u32 mou = sPref;
  u32 mb  = (mou & 0x80000000u) ? (mou & 0x7FFFFFFFu) : ~mou;
  float scale = fmaxf(__uint_as_float(mb), 1e-6f);
  u32 xou = sMax;
  u32 xb  = (xou & 0x80000000u) ? (xou & 0x7FFFFFFFu) : ~xou;
  bool pos = __uint_as_float(xb) > 0.f;
#pragma unroll
  for (int u = 0; u < 4; ++u) {
    int j = tid + u*1024;
    int b = j >> 11, p = j & 2047;
    float r_ = pos ? expf(-m[u]/scale) : 1.f;
    float* ob = out + ((size_t)(b*3 + k)*8)*2048 + p;
#pragma unroll
    for (int f = 0; f < 8; ++f) ob[f*2048] = r_;
  }
}

extern "C" void kernel_launch(void* const* d_in, const int* in_sizes, int n_in,
                              void* d_out, int out_size, void* d_ws, size_t ws_size,
                              hipStream_t stream) {
  (void)in_sizes; (void)n_in; (void)out_size; (void)ws_size;
  const float4* pts = (const float4*)d_in[0];
  float* ws = (float*)d_ws;
  float4* qfw  = (float4*)ws;                     // B*T*P*4   = 114688 floats
  float*  S    = ws + 114688;                     // 3*ROWS    =  86016 floats
  float4* pts2 = (float4*)(ws + 114688 + 86016);  // B*F*P*4   = 131072 floats
  float*  cent = ws + 114688 + 86016 + 131072;    // 16*3      = 48 floats
  float*  M    = ws + 114688 + 86016 + 131072 + 48;  // 3*4096 = 12288 floats
  float*  out = (float*)d_out;

  hipLaunchKernelGGL(kA1_bbox,   dim3(B_*F_), dim3(256), 0, stream, pts, cent);
  hipLaunchKernelGGL(kAB_qfwd,   dim3(ROWS/256), dim3(256), 0, stream, pts, cent, (float4*)qfw, pts2);
  hipLaunchKernelGGL(kC_select,  dim3(ROWS/16), dim3(256), 0, stream, pts2, qfw, S);
  hipLaunchKernelGGL(kE1_means,  dim3(48), dim3(256), 0, stream, S, M);
  hipLaunchKernelGGL(kE2_select, dim3(3), dim3(1024), 0, stream, M, out);
}

// Round 15
// 122.547 us; speedup vs baseline: 1.2664x; 1.2664x over previous
//
#include <hip/hip_runtime.h>
#include <math.h>

typedef unsigned long long u64;
typedef unsigned int u32;

#define B_ 2
#define F_ 8
#define P_ 2048
#define T_ 7                   // F-1
#define ROWS (B_*T_*P_)        // 28672
#define SENT_OU 0xFFFFFFFFu

// ---- keys as doubles: hi word = RAW float bits of nd (>=0 here), lo word = idx.
// For nd >= 0 the double bit pattern is positive, so IEEE double ordering ==
// integer ordering of (nd_bits, idx) == (distance, idx) lexicographic -> exact
// reference order with lower-index tie-break. CE = v_min_f64 + v_max_f64.
// (r8 measured: u64 integer CE is 1.4x MORE VALU cycles; f64 CE is the winner)
#define CED(arr,a,b) do { double _x=arr[a], _y=arr[b]; arr[a]=fmin(_x,_y); arr[b]=fmax(_x,_y); } while(0)

// Batcher odd-even mergesort, 8 elements, 19 comparators
__device__ __forceinline__ void sort8d(double* k) {
  CED(k,0,1); CED(k,2,3); CED(k,4,5); CED(k,6,7);
  CED(k,0,2); CED(k,1,3); CED(k,4,6); CED(k,5,7);
  CED(k,1,2); CED(k,5,6);
  CED(k,0,4); CED(k,1,5); CED(k,2,6); CED(k,3,7);
  CED(k,2,4); CED(k,3,5);
  CED(k,1,2); CED(k,3,4); CED(k,5,6);
}

// A,B sorted ascending -> A = lowest 8 of the 16, sorted
__device__ __forceinline__ void low8(double* A, const double* Bv) {
#pragma unroll
  for (int i = 0; i < 8; ++i) A[i] = fmin(A[i], Bv[7-i]);   // bitonic
#pragma unroll
  for (int st = 4; st >= 1; st >>= 1) {
#pragma unroll
    for (int i = 0; i < 8; ++i) {
      if ((i & st) == 0) { CED(A, i, i + st); }
    }
  }
}

// ---- quarter(16-lane)-local butterfly reductions via DPP: result in ALL lanes ----
__device__ __forceinline__ u32 bfly16_min_u32(u32 x) {
  u32 t;
  t = (u32)__builtin_amdgcn_update_dpp((int)x,(int)x,0x0B1,0xF,0xF,false); x = t<x?t:x;
  t = (u32)__builtin_amdgcn_update_dpp((int)x,(int)x,0x04E,0xF,0xF,false); x = t<x?t:x;
  t = (u32)__builtin_amdgcn_update_dpp((int)x,(int)x,0x141,0xF,0xF,false); x = t<x?t:x;
  t = (u32)__builtin_amdgcn_update_dpp((int)x,(int)x,0x140,0xF,0xF,false); x = t<x?t:x;
  return x;
}
__device__ __forceinline__ float bfly16_sum_f32(float x) {
  float t;
  t = __uint_as_float((u32)__builtin_amdgcn_update_dpp((int)__float_as_uint(x),(int)__float_as_uint(x),0x0B1,0xF,0xF,false)); x += t;
  t = __uint_as_float((u32)__builtin_amdgcn_update_dpp((int)__float_as_uint(x),(int)__float_as_uint(x),0x04E,0xF,0xF,false)); x += t;
  t = __uint_as_float((u32)__builtin_amdgcn_update_dpp((int)__float_as_uint(x),(int)__float_as_uint(x),0x141,0xF,0xF,false)); x += t;
  t = __uint_as_float((u32)__builtin_amdgcn_update_dpp((int)__float_as_uint(x),(int)__float_as_uint(x),0x140,0xF,0xF,false)); x += t;
  return x;
}

// bearing quaternion for one point (identical arithmetic across rounds)
__device__ __forceinline__ float4 bearing(float4 v, float cx, float cy, float cz) {
  float dx=v.x-cx, dy=v.y-cy, dz=v.z-cz;
  float n = sqrtf(((dx*dx) + dy*dy) + dz*dz);
  n = fmaxf(n, 1e-12f);
  float dxn = dx/n, dyn = dy/n, dzn = dz/n;
  float dotc = fminf(fmaxf(dyn, -0.99999990f), 0.99999990f);
  float half = acosf(dotc) * 0.5f;
  float an = sqrtf(dzn*dzn + dxn*dxn);
  an = fmaxf(an, 1e-12f);
  float axx = dzn/an, axz = (-dxn)/an;
  float s = sinf(half), w = cosf(half);
  return make_float4(w, axx*s, 0.f, axz*s);
}

// ---------------- Kernel ABf: fused bbox + bearings + forward quats + pts2 ----
// Each block (one (b,t) tile slice of 256 points) redoes the 2-frame bbox
// reduction in-block (identical load pattern + combine order as the old kA1
// -> bit-identical centroids), then per-point bearing/hamilton as before.
__global__ __launch_bounds__(256) void kABf_qfwd(const float4* __restrict__ pts,
                                                 float4* __restrict__ qf,
                                                 float4* __restrict__ pts2) {
  int i = blockIdx.x*256 + threadIdx.x;   // over B*T*P
  int p = i & (P_-1);
  int t = (i >> 11) % T_;
  int b = i / (T_*P_);
  int bf0 = b*F_ + t;
  int tid = threadIdx.x;
  const float4* base0 = pts + (size_t)bf0 * P_;
  const float4* base1 = pts + (size_t)(bf0+1) * P_;

  // bbox of frame t (src) and t+1 (tgt), kA1-identical reduction
  float mnx0= INFINITY,mny0= INFINITY,mnz0= INFINITY,mxx0=-INFINITY,mxy0=-INFINITY,mxz0=-INFINITY;
  float mnx1= INFINITY,mny1= INFINITY,mnz1= INFINITY,mxx1=-INFINITY,mxy1=-INFINITY,mxz1=-INFINITY;
#pragma unroll
  for (int u = 0; u < 8; ++u) {
    float4 v = base0[tid + u*256];
    mnx0=fminf(mnx0,v.x); mny0=fminf(mny0,v.y); mnz0=fminf(mnz0,v.z);
    mxx0=fmaxf(mxx0,v.x); mxy0=fmaxf(mxy0,v.y); mxz0=fmaxf(mxz0,v.z);
  }
#pragma unroll
  for (int u = 0; u < 8; ++u) {
    float4 v = base1[tid + u*256];
    mnx1=fminf(mnx1,v.x); mny1=fminf(mny1,v.y); mnz1=fminf(mnz1,v.z);
    mxx1=fmaxf(mxx1,v.x); mxy1=fmaxf(mxy1,v.y); mxz1=fmaxf(mxz1,v.z);
  }
#pragma unroll
  for (int off = 32; off >= 1; off >>= 1) {
    mnx0=fminf(mnx0,__shfl_xor(mnx0,off)); mny0=fminf(mny0,__shfl_xor(mny0,off)); mnz0=fminf(mnz0,__shfl_xor(mnz0,off));
    mxx0=fmaxf(mxx0,__shfl_xor(mxx0,off)); mxy0=fmaxf(mxy0,__shfl_xor(mxy0,off)); mxz0=fmaxf(mxz0,__shfl_xor(mxz0,off));
    mnx1=fminf(mnx1,__shfl_xor(mnx1,off)); mny1=fminf(mny1,__shfl_xor(mny1,off)); mnz1=fminf(mnz1,__shfl_xor(mnz1,off));
    mxx1=fmaxf(mxx1,__shfl_xor(mxx1,off)); mxy1=fmaxf(mxy1,__shfl_xor(mxy1,off)); mxz1=fmaxf(mxz1,__shfl_xor(mxz1,off));
  }
  __shared__ float red[4][12];
  int wid = tid >> 6, lane = tid & 63;
  if (lane == 0) {
    red[wid][0]=mnx0; red[wid][1]=mny0; red[wid][2]=mnz0;
    red[wid][3]=mxx0; red[wid][4]=mxy0; red[wid][5]=mxz0;
    red[wid][6]=mnx1; red[wid][7]=mny1; red[wid][8]=mnz1;
    red[wid][9]=mxx1; red[wid][10]=mxy1; red[wid][11]=mxz1;
  }
  __syncthreads();
  // kA1-identical combine (same expression order -> same bits), all threads
  float cx0 = (fminf(fminf(red[0][0],red[1][0]),fminf(red[2][0],red[3][0]))
             + fmaxf(fmaxf(red[0][3],red[1][3]),fmaxf(red[2][3],red[3][3]))) * 0.5f;
  float cy0 = (fminf(fminf(red[0][1],red[1][1]),fminf(red[2][1],red[3][1]))
             + fmaxf(fmaxf(red[0][4],red[1][4]),fmaxf(red[2][4],red[3][4]))) * 0.5f;
  float cz0 = (fminf(fminf(red[0][2],red[1][2]),fminf(red[2][2],red[3][2]))
             + fmaxf(fmaxf(red[0][5],red[1][5]),fmaxf(red[2][5],red[3][5]))) * 0.5f;
  float cx1 = (fminf(fminf(red[0][6],red[1][6]),fminf(red[2][6],red[3][6]))
             + fmaxf(fmaxf(red[0][9],red[1][9]),fmaxf(red[2][9],red[3][9]))) * 0.5f;
  float cy1 = (fminf(fminf(red[0][7],red[1][7]),fminf(red[2][7],red[3][7]))
             + fmaxf(fmaxf(red[0][10],red[1][10]),fmaxf(red[2][10],red[3][10]))) * 0.5f;
  float cz1 = (fminf(fminf(red[0][8],red[1][8]),fminf(red[2][8],red[3][8]))
             + fmaxf(fmaxf(red[0][11],red[1][11]),fmaxf(red[2][11],red[3][11]))) * 0.5f;

  float4 v0 = base0[p];
  float4 v1 = base1[p];
  float4 s = bearing(v0, cx0, cy0, cz0);       // src (frame t)
  float4 a = bearing(v1, cx1, cy1, cz1);       // tgt (frame t+1)
  float aw=a.x, ax=a.y, ay=a.z, az=a.w;
  float bw=s.x, bx=-s.y, by=-s.z, bz=-s.w;     // conj
  float w  = ((aw*bw - ax*bx) - ay*by) - az*bz;
  float xo = ((aw*bx + ax*bw) + ay*bz) - az*by;
  float yo = ((aw*by - ax*bz) + ay*bw) + az*bx;
  float zo = ((aw*bz + ax*by) - ay*bx) + az*bw;
  float n = sqrtf(((w*w + xo*xo) + yo*yo) + zo*zo);
  n = fmaxf(n, 1e-12f);
  qf[i] = make_float4(w/n, xo/n, yo/n, zo/n);
  float qs = fmaf(v0.x,v0.x, fmaf(v0.y,v0.y, v0.z*v0.z));
  pts2[(size_t)bf0*P_ + p] = make_float4(v0.x, v0.y, v0.z, qs);
}

// ---------------- Kernel C: top-40, quarter-wave rows, 4 waves/block ----------------
__device__ __forceinline__ double mkkey(float4 c, u32 q,
                                        float px, float py, float pz, float ps) {
  float dot = fmaf(px, c.x, fmaf(py, c.y, pz*c.z));
  float nd  = fmaf(-2.f, dot, ps + c.w);   // ascending distance (>= 0 here)
  return __hiloint2double(__float_as_int(nd), (int)q);
}
__device__ __forceinline__ u64 mkkey_u(float4 c, u32 q,
                                       float px, float py, float pz, float ps) {
  float dot = fmaf(px, c.x, fmaf(py, c.y, pz*c.z));
  float nd  = fmaf(-2.f, dot, ps + c.w);
  u32 u = __float_as_uint(nd);
  u32 ou = u ^ (((u32)((int)u >> 31)) | 0x80000000u);
  return ((u64)ou << 16) | q;
}

__device__ __forceinline__ void popstep(u32 (&OU)[8], u32 (&IX)[8],
                                        u32& LOU, u32& LIX, u32& CAP, int imod,
                                        int slot, const float4* __restrict__ pbase,
                                        float px, float py, float pz, float ps) {
  if (__any(OU[0] == SENT_OU)) {       // exact refill, cold (P ~ 0.4%/wave over 40 pops)
    bool need = (OU[0] == SENT_OU);
    u64 lastK = ((u64)LOU << 16) | LIX;
    u64 best = ~0ull;
    for (int j = 0; j < 128; ++j) {
      u32 q = (u32)(j*16 + slot);
      u64 kk = mkkey_u(pbase[q], q, px,py,pz,ps);
      if (kk > lastK && kk < best) best = kk;
    }
    if (need && best != ~0ull) {
      OU[0] = (u32)(best >> 16); IX[0] = (u32)(best & 0xffffu);
      LOU = OU[0]; LIX = IX[0];        // next-refill anchor for this lane
    }
  }
  u32 qmin = bfly16_min_u32(OU[0]);                  // all lanes get quarter min ou
  bool meq = (OU[0] == qmin);
  u32 tt   = meq ? IX[0] : 0xFFFFFFFFu;
  u32 widx = bfly16_min_u32(tt);                     // exact idx tie-break + broadcast
  bool iam = meq && (IX[0] == widx);
  CAP = (slot == imod) ? widx : CAP;
#pragma unroll
  for (int jj = 0; jj < 7; ++jj) {
    OU[jj] = iam ? OU[jj+1] : OU[jj];
    IX[jj] = iam ? IX[jj+1] : IX[jj];
  }
  OU[7] = iam ? SENT_OU : OU[7];
}

__global__ __launch_bounds__(256) void kC_select(const float4* __restrict__ pts2,
                                                 const float4* __restrict__ qf,
                                                 float* __restrict__ S) {
  int lane = threadIdx.x & 63;
  int wid  = threadIdx.x >> 6;         // wave within block (0..3)
  int slot = lane & 15;                // position within 16-lane quarter
  int quarter = lane >> 4;             // 0..3
  int gid = blockIdx.x * 16 + wid * 4; // first row of this wave
  int p0 = gid & (P_-1);               // 16 divides 2048 -> same tile across waves
  int bt = gid >> 11;                  // b*7 + t
  int t  = bt % T_;
  int b  = bt / T_;
  const float4* pbase = pts2 + (size_t)(b*F_ + t) * P_;

  int prow = p0 + quarter;             // this quarter's row
  float4 pw = pbase[prow];
  float px=pw.x, py=pw.y, pz=pw.z, ps=pw.w;

  // ---- sort phase: per lane 128 candidates (j*16+slot), keep sorted top-8 ----
  double acc[8];
  {
    double k0[8];
#pragma unroll
    for (int u = 0; u < 8; ++u) { float4 c = pbase[u*16 + slot];
      k0[u] = mkkey(c, (u32)(u*16 + slot), px,py,pz,ps); }
    sort8d(k0);
#pragma unroll
    for (int j = 0; j < 8; ++j) acc[j] = k0[j];
  }
#pragma unroll 2
  for (int batch = 1; batch < 16; ++batch) {
    int qb = batch*128 + slot;
    float4 c[8];
#pragma unroll
    for (int u = 0; u < 8; ++u) c[u] = pbase[qb + u*16];
    double k[8];
#pragma unroll
    for (int u = 0; u < 8; ++u) k[u] = mkkey(c[u], (u32)(qb + u*16), px,py,pz,ps);
    sort8d(k);
    low8(acc, k);
  }

  // unpack into register queue; transform raw nd bits -> ordered u32 (8 entries
  // only, vs per-candidate in the hot loop); refill anchor = acc[7]
  u32 OU[8], IX[8];
#pragma unroll
  for (int j = 0; j < 8; ++j) {
    u64 bb = (u64)__double_as_longlong(acc[j]);
    u32 hi = (u32)(bb >> 32);
    OU[j] = hi ^ (((u32)((int)hi >> 31)) | 0x80000000u);
    IX[j] = (u32)(bb & 0xffffu);
  }
  u32 lou = OU[7], lix = IX[7];
  u32 cap1=0, cap2=0, cap3=0;

#pragma unroll 1
  for (int i = 0; i < 16; ++i)         // winners 0..15 -> cap1[slot==i]
    popstep(OU, IX, lou, lix, cap1, i, slot, pbase, px,py,pz,ps);
#pragma unroll 1
  for (int i = 0; i < 16; ++i)         // winners 16..31 -> cap2
    popstep(OU, IX, lou, lix, cap2, i, slot, pbase, px,py,pz,ps);
#pragma unroll 1
  for (int i = 0; i < 8; ++i)          // winners 32..39 -> cap3 (slots 0..7)
    popstep(OU, IX, lou, lix, cap3, i, slot, pbase, px,py,pz,ps);

  // ---- epilogue: geodesic sums ----
  int row = bt*P_ + prow;
  const float4* qbt = qf + (size_t)bt * P_;
  float4 qp = qf[row];

  float4 n; float d;
  n = qbt[cap1]; d = ((qp.x*n.x + qp.y*n.y) + qp.z*n.z) + qp.w*n.w;
  float g1 = 2.f * acosf(fminf(fabsf(d), 0.99999990f));
  n = qbt[cap2]; d = ((qp.x*n.x + qp.y*n.y) + qp.z*n.z) + qp.w*n.w;
  float g2 = 2.f * acosf(fminf(fabsf(d), 0.99999990f));
  n = qbt[cap3]; d = ((qp.x*n.x + qp.y*n.y) + qp.z*n.z) + qp.w*n.w;
  float g3 = (slot < 8) ? 2.f * acosf(fminf(fabsf(d), 0.99999990f)) : 0.f;

  float s40 = bfly16_sum_f32(g1 + g2 + g3);
  float s15 = bfly16_sum_f32((slot < 15) ? g1 : 0.f);
  float s5  = bfly16_sum_f32((slot < 5)  ? g1 : 0.f);

  if (slot == 0) {
    S[0*ROWS + row] = s5  / 5.f;
    S[1*ROWS + row] = s15 / 15.f;
    S[2*ROWS + row] = s40 / 40.f;
  }
}

// ---------------- Kernel E: mean over t, median, output (1 block per scale) ----
__global__ __launch_bounds__(1024) void kE_final(const float* __restrict__ S,
                                                 float* __restrict__ out) {
  int k = blockIdx.x;                  // scale index 0..2
  int tid = threadIdx.x;
  __shared__ float srt[4096];
  const float* Sk = S + (size_t)k * ROWS;
  float m[4];
#pragma unroll
  for (int u = 0; u < 4; ++u) {
    int j = tid + u*1024;              // j = b*2048 + p
    int b = j >> 11, p = j & 2047;
    float acc = 0.f;
#pragma unroll
    for (int t = 0; t < 7; ++t) acc += Sk[(b*7 + t)*2048 + p];
    m[u] = acc / 7.f;
    srt[j] = m[u];
  }
  __syncthreads();
  for (int size = 2; size <= 4096; size <<= 1) {
    for (int stride = size >> 1; stride > 0; stride >>= 1) {
      for (int c = tid; c < 2048; c += 1024) {
        int i = 2*c - (c & (stride - 1));
        int j = i + stride;
        bool up = ((i & size) == 0);
        float a = srt[i], bb = srt[j];
        if ((a > bb) == up) { srt[i] = bb; srt[j] = a; }
      }
      __syncthreads();
    }
  }
  float scale = fmaxf(srt[2047], 1e-6f);   // lower median of 4096
  bool pos = srt[4095] > 0.f;
#pragma unroll
  for (int u = 0; u < 4; ++u) {
    int j = tid + u*1024;
    int b = j >> 11, p = j & 2047;
    float r = pos ? expf(-m[u]/scale) : 1.f;
    float* ob = out + ((size_t)(b*3 + k)*8)*2048 + p;
#pragma unroll
    for (int f = 0; f < 8; ++f) ob[f*2048] = r;
  }
}

extern "C" void kernel_launch(void* const* d_in, const int* in_sizes, int n_in,
                              void* d_out, int out_size, void* d_ws, size_t ws_size,
                              hipStream_t stream) {
  (void)in_sizes; (void)n_in; (void)out_size; (void)ws_size;
  const float4* pts = (const float4*)d_in[0];
  float* ws = (float*)d_ws;
  float4* qfw  = (float4*)ws;                     // B*T*P*4   = 114688 floats
  float*  S    = ws + 114688;                     // 3*ROWS    =  86016 floats
  float4* pts2 = (float4*)(ws + 114688 + 86016);  // B*F*P*4   = 131072 floats
  float*  out = (float*)d_out;

  hipLaunchKernelGGL(kABf_qfwd, dim3(ROWS/256), dim3(256), 0, stream, pts, (float4*)qfw, pts2);
  hipLaunchKernelGGL(kC_select, dim3(ROWS/16), dim3(256), 0, stream, pts2, qfw, S);
  hipLaunchKernelGGL(kE_final,  dim3(3), dim3(1024), 0, stream, S, out);
}